// Round 6
// baseline (1484.053 us; speedup 1.0000x reference)
//
#include <hip/hip_runtime.h>
#include <math.h>

#define H 1536
#define E 512
#define T 48
#define S 32
#define V 128
#define NB 256
#define BT 768     // 12 waves
#define NW 12
#define JPB 6      // H / NB
#define ROWS 24    // 4*JPB gate rows per block
#define NC 32      // replicated h-exchange copies (8 readers per copy line)

__device__ __forceinline__ float sigf(float x) { return 1.0f / (1.0f + expf(-x)); }
__device__ __forceinline__ float dot4(float4 a, float4 b) {
    return a.x * b.x + a.y * b.y + a.z * b.z + a.w * b.w;
}
__device__ __forceinline__ float wred(float acc) {
#pragma unroll
    for (int off = 32; off; off >>= 1) acc += __shfl_down(acc, off);
    return acc;
}

// Cross-block data: relaxed agent-scope atomics -> cache-bypass to the coherent
// point (MALL). Weights stay cached in L2/L3 (no fences, no buffer_inv).
#define GLD(p)    __hip_atomic_load((p), __ATOMIC_RELAXED, __HIP_MEMORY_SCOPE_AGENT)
#define GST(p, v) __hip_atomic_store((p), (v), __ATOMIC_RELAXED, __HIP_MEMORY_SCOPE_AGENT)

// Distributed-arrival / distributed-release grid barrier (round 4/5 design;
// arrival + release were shown NOT to be the bottleneck). Data-before-flag:
// __syncthreads() drains each wave's vmcnt before s_barrier, so all blocks'
// agent-scope stores are at the coherence point before the arrival store.
__device__ __forceinline__ void gbar(unsigned* flags, unsigned* rel, unsigned& gen) {
    __syncthreads();
    gen++;
    if (blockIdx.x == 0) {
        if (threadIdx.x < 64) {
            const int i0 = threadIdx.x * 4;
            for (;;) {
                unsigned a0 = (i0 == 0) ? gen : GLD(&flags[(i0 + 0) * 16]);
                unsigned a1 = GLD(&flags[(i0 + 1) * 16]);
                unsigned a2 = GLD(&flags[(i0 + 2) * 16]);
                unsigned a3 = GLD(&flags[(i0 + 3) * 16]);
                bool ok = (a0 >= gen) && (a1 >= gen) && (a2 >= gen) && (a3 >= gen);
                if (__all(ok)) break;
                __builtin_amdgcn_s_sleep(1);
            }
#pragma unroll
            for (int k = 0; k < 4; ++k) GST(&rel[(i0 + k) * 16], gen);
        }
    } else {
        if (threadIdx.x == 0) {
            GST(&flags[blockIdx.x * 16], gen);
            while (GLD(&rel[blockIdx.x * 16]) < gen) __builtin_amdgcn_s_sleep(1);
        }
    }
    __syncthreads();
}

__global__ void init_kernel(unsigned* u) {
    // zero flags (256*16) + release slots (256*16)
    for (int i = threadIdx.x; i < 8192; i += 256) u[i] = 0u;
}

// ws 32-bit words: [0..4096) release | [4096..8192) flags |
//                  [8192..) h1 copies NC*H | h2 copies NC*H
__global__ __launch_bounds__(BT, 3) void nas_persist(
    const int* __restrict__ input_id, const float* __restrict__ emb,
    const float* __restrict__ Wih1, const float* __restrict__ Whh1,
    const float* __restrict__ bih1, const float* __restrict__ bhh1,
    const float* __restrict__ Wih2, const float* __restrict__ Whh2,
    const float* __restrict__ bih2, const float* __restrict__ bhh2,
    const float* __restrict__ Wout, const float* __restrict__ bout,
    float* __restrict__ out, float* __restrict__ ws)
{
    const int b = blockIdx.x, tid = threadIdx.x;
    const int wave = tid >> 6, lane = tid & 63;
    const int mycopy = b & (NC - 1);

    unsigned* rel   = (unsigned*)ws;
    unsigned* flags = (unsigned*)ws + 4096;
    float* h1c = ws + 8192;                    // NC copies of h1 (replicated)
    float* h2c = ws + 8192 + NC * H;           // NC copies of h2

    __shared__ float4 lds_emb4[2048];        // 32 KB, prologue only
    __shared__ float  xw1_lds[V * ROWS];     // 12 KB: xw1[v][k], biases folded
    __shared__ float4 lds_h1_4[H / 4];       // 6 KB
    __shared__ float4 lds_h2_4[H / 4];       // 6 KB
    __shared__ float  gacc1[ROWS], g2f[ROWS], bsum2[ROWS], zlog[S];
    __shared__ float  c1s[JPB], c2s[JPB];
    __shared__ float  h1own[JPB], h2own[JPB];
    __shared__ int    xid_s;

    float* lds_h1 = (float*)lds_h1_4;
    float* lds_h2 = (float*)lds_h2_4;

    unsigned gen = 0;

    // ---------------- prologue ----------------
    for (int i = tid; i < H; i += BT) lds_h2[i] = 0.0f;   // h2(-1) = 0
    if (tid < JPB) { c1s[tid] = 0.f; c2s[tid] = 0.f; }
    if (tid < ROWS) {
        int r = (tid / JPB) * H + b * JPB + (tid % JPB);
        bsum2[tid] = bih2[r] + bhh2[r];
    }

    // xw1_lds[v][k] = dot(Wih1[r(k)], emb[v]) + bih1 + bhh1 for this block's rows
    {
        const int k0 = wave * 2, k1 = k0 + 1;
        const int r0 = (k0 / JPB) * H + b * JPB + (k0 % JPB);
        const int r1 = (k1 / JPB) * H + b * JPB + (k1 % JPB);
        const float4* w0 = (const float4*)(Wih1 + (size_t)r0 * E);
        const float4* w1 = (const float4*)(Wih1 + (size_t)r1 * E);
        float4 w0a = w0[lane], w0b = w0[lane + 64];
        float4 w1a = w1[lane], w1b = w1[lane + 64];
        float bs0 = bih1[r0] + bhh1[r0];
        float bs1 = bih1[r1] + bhh1[r1];
        for (int ch = 0; ch < 8; ++ch) {               // 16 emb rows per chunk
            const float4* src = (const float4*)(emb + (size_t)ch * 16 * E);
            for (int i = tid; i < 2048; i += BT) lds_emb4[i] = src[i];
            __syncthreads();
            for (int vv = 0; vv < 16; ++vv) {
                float4 ea = lds_emb4[vv * 128 + lane];
                float4 eb = lds_emb4[vv * 128 + 64 + lane];
                float a0 = wred(dot4(w0a, ea) + dot4(w0b, eb));
                float a1 = wred(dot4(w1a, ea) + dot4(w1b, eb));
                if (lane == 0) {
                    int v = ch * 16 + vv;
                    xw1_lds[v * ROWS + k0] = a0 + bs0;
                    xw1_lds[v * ROWS + k1] = a1 + bs1;
                }
            }
            __syncthreads();
        }
    }

    // h1(0) = cell1 with h(-1)=0, c(-1)=0
    if (tid == 0) xid_s = *input_id;
    __syncthreads();
    if (tid < JPB) {
        const float* xr = &xw1_lds[xid_s * ROWS];
        float gi = xr[tid], gg = xr[2 * JPB + tid], go = xr[3 * JPB + tid];
        float cn = sigf(gi) * tanhf(gg);
        c1s[tid] = cn;
        h1own[tid] = sigf(go) * tanhf(cn);
    }
    __syncthreads();
    if (tid < JPB * NC) {                       // replicate to all copies
        int c = tid / JPB, e = tid % JPB;
        GST(h1c + (size_t)c * H + b * JPB + e, h1own[e]);
    }
    gbar(flags, rel, gen);

    for (int t = 0; t < T; ++t) {
        // ---------- phase X: all three HxH matvecs + cell2 pointwise ----------
        for (int i = tid; i < H; i += BT) lds_h1[i] = GLD(h1c + (size_t)mycopy * H + i);
        __syncthreads();
        {
            const int k0 = wave * 2, k1 = k0 + 1;
            const int r0 = (k0 / JPB) * H + b * JPB + (k0 % JPB);
            const int r1 = (k1 / JPB) * H + b * JPB + (k1 % JPB);
            const float4* x1 = (const float4*)lds_h1;
            const float4* x2 = (const float4*)lds_h2;

            auto rowdot = [&](const float* Wp, int r, const float4* x) {
                const float4* wr = (const float4*)(Wp + (size_t)r * H);
                float acc = 0.f;
#pragma unroll
                for (int i = 0; i < 6; ++i) acc += dot4(wr[lane + 64 * i], x[lane + 64 * i]);
                return wred(acc);
            };

            float d_ih2_0 = rowdot(Wih2, r0, x1);
            float d_ih2_1 = rowdot(Wih2, r1, x1);
            float d_hh2_0 = rowdot(Whh2, r0, x2);
            float d_hh2_1 = rowdot(Whh2, r1, x2);
            float d_hh1_0 = rowdot(Whh1, r0, x1);   // for cell1 at t+1
            float d_hh1_1 = rowdot(Whh1, r1, x1);
            if (lane == 0) {
                g2f[k0] = d_ih2_0 + d_hh2_0 + bsum2[k0];
                g2f[k1] = d_ih2_1 + d_hh2_1 + bsum2[k1];
                gacc1[k0] = d_hh1_0;
                gacc1[k1] = d_hh1_1;
            }
        }
        __syncthreads();
        if (tid < JPB) {
            float gi = g2f[tid],           gf = g2f[JPB + tid];
            float gg = g2f[2 * JPB + tid], go = g2f[3 * JPB + tid];
            float cn = sigf(gf) * c2s[tid] + sigf(gi) * tanhf(gg);
            c2s[tid] = cn;
            h2own[tid] = sigf(go) * tanhf(cn);
        }
        __syncthreads();
        if (tid < JPB * NC) {
            int c = tid / JPB, e = tid % JPB;
            GST(h2c + (size_t)c * H + b * JPB + e, h2own[e]);
        }
        gbar(flags, rel, gen);

        // ---------- phase Y: redundant head + cell1 pointwise for t+1 ----------
        for (int i = tid; i < H; i += BT) lds_h2[i] = GLD(h2c + (size_t)mycopy * H + i);
        __syncthreads();
        {
            const float4* x2 = (const float4*)lds_h2;
            for (int s = wave; s < S; s += NW) {
                const float4* wo = (const float4*)(Wout + ((size_t)t * S + s) * H);
                float acc = 0.f;
#pragma unroll
                for (int i = 0; i < 6; ++i) acc += dot4(wo[lane + 64 * i], x2[lane + 64 * i]);
                acc = wred(acc);
                if (lane == 0) zlog[s] = acc + bout[t * S + s];
            }
        }
        __syncthreads();
        if (wave == 0) {
            float z = (lane < S) ? zlog[lane] : -1e30f;
            float v = z; int idx = (lane < S) ? lane : 9999;
#pragma unroll
            for (int off = 32; off; off >>= 1) {
                float ov = __shfl_xor(v, off); int oi = __shfl_xor(idx, off);
                if (ov > v || (ov == v && oi < idx)) { v = ov; idx = oi; }
            }
            float e = (lane < S) ? expf(z - v) : 0.f;
#pragma unroll
            for (int off = 32; off; off >>= 1) e += __shfl_xor(e, off);
            if (lane == 0) xid_s = (t & 3) * S + idx;
            if (b == 0 && lane < S) out[(size_t)t * S + lane] = z - v - logf(e);
        }
        __syncthreads();
        if (tid < JPB) {
            const float* xr = &xw1_lds[xid_s * ROWS];
            float gi = gacc1[tid]           + xr[tid];
            float gf = gacc1[JPB + tid]     + xr[JPB + tid];
            float gg = gacc1[2 * JPB + tid] + xr[2 * JPB + tid];
            float go = gacc1[3 * JPB + tid] + xr[3 * JPB + tid];
            float cn = sigf(gf) * c1s[tid] + sigf(gi) * tanhf(gg);
            c1s[tid] = cn;
            h1own[tid] = sigf(go) * tanhf(cn);
        }
        __syncthreads();
        if (tid < JPB * NC) {
            int c = tid / JPB, e = tid % JPB;
            GST(h1c + (size_t)c * H + b * JPB + e, h1own[e]);
        }
        gbar(flags, rel, gen);
    }
}

extern "C" void kernel_launch(void* const* d_in, const int* in_sizes, int n_in,
                              void* d_out, int out_size, void* d_ws, size_t ws_size,
                              hipStream_t stream) {
    const int*   input_id = (const int*)d_in[0];
    const float* emb  = (const float*)d_in[1];
    const float* Wih1 = (const float*)d_in[2];
    const float* Whh1 = (const float*)d_in[3];
    const float* bih1 = (const float*)d_in[4];
    const float* bhh1 = (const float*)d_in[5];
    const float* Wih2 = (const float*)d_in[6];
    const float* Whh2 = (const float*)d_in[7];
    const float* bih2 = (const float*)d_in[8];
    const float* bhh2 = (const float*)d_in[9];
    const float* Wout = (const float*)d_in[10];
    const float* bout = (const float*)d_in[11];
    float* out = (float*)d_out;
    float* ws  = (float*)d_ws;

    init_kernel<<<1, 256, 0, stream>>>((unsigned*)ws);

    void* args[] = { (void*)&input_id, (void*)&emb,
                     (void*)&Wih1, (void*)&Whh1, (void*)&bih1, (void*)&bhh1,
                     (void*)&Wih2, (void*)&Whh2, (void*)&bih2, (void*)&bhh2,
                     (void*)&Wout, (void*)&bout, (void*)&out, (void*)&ws };
    hipLaunchCooperativeKernel((void*)nas_persist, dim3(NB), dim3(BT), args, 0, stream);
}

// Round 7
// 1220.639 us; speedup vs baseline: 1.2158x; 1.2158x over previous
//
#include <hip/hip_runtime.h>
#include <math.h>

#define H 1536
#define E 512
#define T 48
#define S 32
#define V 128
#define NB 256
#define BT 512      // 8 waves
#define NWV 8
#define JPB 6       // h indices per block
#define ROWS 24     // 4*JPB gate rows per block (per matrix)
#define RPW 3       // rows per wave per matrix
#define CHK 24      // floats per lane chunk (1536/64)
// dynamic LDS: whh2 (64 lanes * 145 float4) + h1 chunks (64*7 f4) + h2 chunks
#define WHH2_B   (64 * 145 * 16)          // 148480
#define HBUF_B   (64 * 7 * 16)            // 7168
#define DYN_LDS  (WHH2_B + 2 * HBUF_B)    // 162816

__device__ __forceinline__ float sigf(float x) { return 1.0f / (1.0f + expf(-x)); }
__device__ __forceinline__ float wred(float acc) {
#pragma unroll
    for (int off = 32; off; off >>= 1) acc += __shfl_down(acc, off);
    return acc;
}

// Agent-scope relaxed ops: bypass L1/L2 to the coherent point. Only used for
// h exchange + barrier words; weights stay in regs/LDS/L2.
#define GLD(p)    __hip_atomic_load((p), __ATOMIC_RELAXED, __HIP_MEMORY_SCOPE_AGENT)
#define GST(p, v) __hip_atomic_store((p), (v), __ATOMIC_RELAXED, __HIP_MEMORY_SCOPE_AGENT)

// Distributed-arrival/release barrier (rounds 4-6, correctness validated).
__device__ __forceinline__ void gbar(unsigned* flags, unsigned* rel, unsigned& gen) {
    __syncthreads();
    gen++;
    if (blockIdx.x == 0) {
        if (threadIdx.x < 64) {
            const int i0 = threadIdx.x * 4;
            for (;;) {
                unsigned a0 = (i0 == 0) ? gen : GLD(&flags[(i0 + 0) * 16]);
                unsigned a1 = GLD(&flags[(i0 + 1) * 16]);
                unsigned a2 = GLD(&flags[(i0 + 2) * 16]);
                unsigned a3 = GLD(&flags[(i0 + 3) * 16]);
                bool ok = (a0 >= gen) && (a1 >= gen) && (a2 >= gen) && (a3 >= gen);
                if (__all(ok)) break;
                __builtin_amdgcn_s_sleep(1);
            }
#pragma unroll
            for (int k = 0; k < 4; ++k) GST(&rel[(i0 + k) * 16], gen);
        }
    } else {
        if (threadIdx.x == 0) {
            GST(&flags[blockIdx.x * 16], gen);
            while (GLD(&rel[blockIdx.x * 16]) < gen) __builtin_amdgcn_s_sleep(1);
        }
    }
    __syncthreads();
}

__global__ void init_kernel(unsigned* u) {
    for (int i = threadIdx.x; i < 8192; i += 256) u[i] = 0u;   // rel + flags
}

// ws words: [0..4096) rel | [4096..8192) flags | [8192) h1g[H] | h2g[H] |
//           [16384) xw1g: NB * V * 24 floats
__global__ __launch_bounds__(BT, 2) void nas_persist(
    const int* __restrict__ input_id, const float* __restrict__ emb,
    const float* __restrict__ Wih1, const float* __restrict__ Whh1,
    const float* __restrict__ bih1, const float* __restrict__ bhh1,
    const float* __restrict__ Wih2, const float* __restrict__ Whh2,
    const float* __restrict__ bih2, const float* __restrict__ bhh2,
    const float* __restrict__ Wout, const float* __restrict__ bout,
    float* __restrict__ out, float* __restrict__ ws)
{
    const int b = blockIdx.x, tid = threadIdx.x;
    const int wave = tid >> 6, lane = tid & 63;

    unsigned* rel   = (unsigned*)ws;
    unsigned* flags = (unsigned*)ws + 4096;
    float* h1g  = ws + 8192;
    float* h2g  = ws + 8192 + H;
    float* xw1g = ws + 16384 + (size_t)b * (V * ROWS);

    extern __shared__ char dyn_lds[];
    float4* whh2s = (float4*)dyn_lds;                       // [l*145 + k*6 + j]
    float*  h1s   = (float*)(dyn_lds + WHH2_B);             // chunked, stride 28
    float*  h2s   = (float*)(dyn_lds + WHH2_B + HBUF_B);

    __shared__ float gacc1[ROWS], g2f[ROWS], bsum2[ROWS], zlog[S], xr[ROWS];
    __shared__ float c1s[JPB], c2s[JPB];
    __shared__ int   xid_s;

    unsigned gen = 0;

    // ---------------- prologue ----------------
    if (tid < JPB) { c1s[tid] = 0.f; c2s[tid] = 0.f; }
    if (tid < ROWS) {
        int r = (tid / JPB) * H + b * JPB + (tid % JPB);
        bsum2[tid] = bih2[r] + bhh2[r];
    }
    if (tid == 0) xid_s = *input_id;

    // ---- xw1 table -> global ws (uses whh2s region as emb staging) ----
    {
        const int k0 = wave * RPW;
        float4 wiA[RPW], wiB[RPW];
        float  bs[RPW];
#pragma unroll
        for (int i = 0; i < RPW; ++i) {
            int k = k0 + i;
            int r = (k / JPB) * H + b * JPB + (k % JPB);
            const float4* w = (const float4*)(Wih1 + (size_t)r * E);
            wiA[i] = w[lane]; wiB[i] = w[lane + 64];
            bs[i]  = bih1[r] + bhh1[r];
        }
        float4* stage = (float4*)dyn_lds;                   // 2048 f4 = 32 KB
        for (int ch = 0; ch < 8; ++ch) {
            const float4* src = (const float4*)(emb + (size_t)ch * 16 * E);
            for (int m = tid; m < 2048; m += BT) stage[m] = src[m];
            __syncthreads();
            for (int vv = 0; vv < 16; ++vv) {
                float4 ea = stage[vv * 128 + lane];
                float4 eb = stage[vv * 128 + 64 + lane];
#pragma unroll
                for (int i = 0; i < RPW; ++i) {
                    float a = wiA[i].x * ea.x + wiA[i].y * ea.y + wiA[i].z * ea.z + wiA[i].w * ea.w
                            + wiB[i].x * eb.x + wiB[i].y * eb.y + wiB[i].z * eb.z + wiB[i].w * eb.w;
                    a = wred(a);
                    if (lane == 0) xw1g[(ch * 16 + vv) * ROWS + (k0 + i)] = a + bs[i];
                }
            }
            __syncthreads();
        }
    }

    // ---- Whh2 -> LDS (lane-chunked, odd-f4 stride 145) ----
    for (int k = 0; k < ROWS; ++k) {
        int r = (k / JPB) * H + b * JPB + (k % JPB);
        const float4* src = (const float4*)(Whh2 + (size_t)r * H);
        if (tid < 384) {
            int l = tid / 6, j = tid % 6;
            whh2s[l * 145 + k * 6 + j] = src[tid];
        }
    }
    __syncthreads();

    // ---- Whh1 + Wih2 rows -> registers (144 VGPRs/thread) ----
    float w1[RPW][CHK], w2[RPW][CHK];
#pragma unroll
    for (int i = 0; i < RPW; ++i) {
        int k = wave * RPW + i;
        int r = (k / JPB) * H + b * JPB + (k % JPB);
        const float4* p1 = (const float4*)(Whh1 + (size_t)r * H) + lane * 6;
        const float4* p2 = (const float4*)(Wih2 + (size_t)r * H) + lane * 6;
#pragma unroll
        for (int j = 0; j < 6; ++j) {
            float4 v1 = p1[j], v2 = p2[j];
            w1[i][4 * j + 0] = v1.x; w1[i][4 * j + 1] = v1.y;
            w1[i][4 * j + 2] = v1.z; w1[i][4 * j + 3] = v1.w;
            w2[i][4 * j + 0] = v2.x; w2[i][4 * j + 1] = v2.y;
            w2[i][4 * j + 2] = v2.z; w2[i][4 * j + 3] = v2.w;
        }
    }

    float h2c[CHK];
#pragma unroll
    for (int k = 0; k < CHK; ++k) h2c[k] = 0.f;     // h2(-1) = 0

    // ---- initial cell1 (h1(-1)=0, c1(-1)=0) ----
    __syncthreads();
    if (tid < ROWS) xr[tid] = xw1g[xid_s * ROWS + tid];
    __syncthreads();
    if (tid < JPB) {
        float gi = xr[tid], gg = xr[2 * JPB + tid], go = xr[3 * JPB + tid];
        float cn = sigf(gi) * tanhf(gg);
        c1s[tid] = cn;
        GST(h1g + b * JPB + tid, sigf(go) * tanhf(cn));
    }
    gbar(flags, rel, gen);

    for (int t = 0; t < T; ++t) {
        // ---------- phase X: 3 HxH matvecs + cell2 pointwise ----------
        for (int i = tid; i < H; i += BT)
            h1s[(i / CHK) * 28 + (i % CHK)] = GLD(h1g + i);
        __syncthreads();

        float h1c[CHK];
        {
            const float4* hp = (const float4*)h1s + lane * 7;
#pragma unroll
            for (int j = 0; j < 6; ++j) {
                float4 v = hp[j];
                h1c[4 * j + 0] = v.x; h1c[4 * j + 1] = v.y;
                h1c[4 * j + 2] = v.z; h1c[4 * j + 3] = v.w;
            }
        }
        float a1[RPW], a2[RPW];
#pragma unroll
        for (int i = 0; i < RPW; ++i) { a1[i] = 0.f; a2[i] = 0.f; }
#pragma unroll
        for (int k = 0; k < CHK; ++k) {
            float h = h1c[k];
#pragma unroll
            for (int i = 0; i < RPW; ++i) {
                a1[i] += w1[i][k] * h;
                a2[i] += w2[i][k] * h;
            }
        }
#pragma unroll
        for (int i = 0; i < RPW; ++i) {
            int k = wave * RPW + i;
            const float4* wp = whh2s + lane * 145 + k * 6;
            float ah = 0.f;
#pragma unroll
            for (int j = 0; j < 6; ++j) {
                float4 v = wp[j];
                ah += v.x * h2c[4 * j + 0] + v.y * h2c[4 * j + 1]
                    + v.z * h2c[4 * j + 2] + v.w * h2c[4 * j + 3];
            }
            float s1 = wred(a1[i]);
            float s2 = wred(a2[i] + ah);
            if (lane == 0) {
                gacc1[k] = s1;
                g2f[k]   = s2 + bsum2[k];
            }
        }
        __syncthreads();
        if (tid < JPB) {
            float gi = g2f[tid],           gf = g2f[JPB + tid];
            float gg = g2f[2 * JPB + tid], go = g2f[3 * JPB + tid];
            float cn = sigf(gf) * c2s[tid] + sigf(gi) * tanhf(gg);
            c2s[tid] = cn;
            GST(h2g + b * JPB + tid, sigf(go) * tanhf(cn));
        }
        gbar(flags, rel, gen);

        // ---------- phase Y: head (redundant) + cell1 pointwise ----------
        for (int i = tid; i < H; i += BT)
            h2s[(i / CHK) * 28 + (i % CHK)] = GLD(h2g + i);
        __syncthreads();
        {
            const float4* hp = (const float4*)h2s + lane * 7;
#pragma unroll
            for (int j = 0; j < 6; ++j) {
                float4 v = hp[j];
                h2c[4 * j + 0] = v.x; h2c[4 * j + 1] = v.y;
                h2c[4 * j + 2] = v.z; h2c[4 * j + 3] = v.w;
            }
        }
#pragma unroll
        for (int q = 0; q < 4; ++q) {
            int s = wave * 4 + q;
            const float4* wo = (const float4*)(Wout + ((size_t)t * S + s) * H) + lane * 6;
            float acc = 0.f;
#pragma unroll
            for (int j = 0; j < 6; ++j) {
                float4 v = wo[j];
                acc += v.x * h2c[4 * j + 0] + v.y * h2c[4 * j + 1]
                     + v.z * h2c[4 * j + 2] + v.w * h2c[4 * j + 3];
            }
            acc = wred(acc);
            if (lane == 0) zlog[s] = acc + bout[t * S + s];
        }
        __syncthreads();
        if (wave == 0) {
            float z = (lane < S) ? zlog[lane] : -1e30f;
            float v = z; int idx = (lane < S) ? lane : 9999;
#pragma unroll
            for (int off = 32; off; off >>= 1) {
                float ov = __shfl_xor(v, off); int oi = __shfl_xor(idx, off);
                if (ov > v || (ov == v && oi < idx)) { v = ov; idx = oi; }
            }
            float e = (lane < S) ? expf(z - v) : 0.f;
#pragma unroll
            for (int off = 32; off; off >>= 1) e += __shfl_xor(e, off);
            if (lane == 0) xid_s = (t & 3) * S + idx;
            if (b == 0 && lane < S) out[(size_t)t * S + lane] = z - v - logf(e);
        }
        __syncthreads();
        if (tid < ROWS) xr[tid] = xw1g[xid_s * ROWS + tid];
        __syncthreads();
        if (tid < JPB) {
            float gi = gacc1[tid]           + xr[tid];
            float gf = gacc1[JPB + tid]     + xr[JPB + tid];
            float gg = gacc1[2 * JPB + tid] + xr[2 * JPB + tid];
            float go = gacc1[3 * JPB + tid] + xr[3 * JPB + tid];
            float cn = sigf(gf) * c1s[tid] + sigf(gi) * tanhf(gg);
            c1s[tid] = cn;
            GST(h1g + b * JPB + tid, sigf(go) * tanhf(cn));
        }
        gbar(flags, rel, gen);
    }
}

extern "C" void kernel_launch(void* const* d_in, const int* in_sizes, int n_in,
                              void* d_out, int out_size, void* d_ws, size_t ws_size,
                              hipStream_t stream) {
    const int*   input_id = (const int*)d_in[0];
    const float* emb  = (const float*)d_in[1];
    const float* Wih1 = (const float*)d_in[2];
    const float* Whh1 = (const float*)d_in[3];
    const float* bih1 = (const float*)d_in[4];
    const float* bhh1 = (const float*)d_in[5];
    const float* Wih2 = (const float*)d_in[6];
    const float* Whh2 = (const float*)d_in[7];
    const float* bih2 = (const float*)d_in[8];
    const float* bhh2 = (const float*)d_in[9];
    const float* Wout = (const float*)d_in[10];
    const float* bout = (const float*)d_in[11];
    float* out = (float*)d_out;
    float* ws  = (float*)d_ws;

    init_kernel<<<1, 256, 0, stream>>>((unsigned*)ws);

    void* args[] = { (void*)&input_id, (void*)&emb,
                     (void*)&Wih1, (void*)&Whh1, (void*)&bih1, (void*)&bhh1,
                     (void*)&Wih2, (void*)&Whh2, (void*)&bih2, (void*)&bhh2,
                     (void*)&Wout, (void*)&bout, (void*)&out, (void*)&ws };
    hipLaunchCooperativeKernel((void*)nas_persist, dim3(NB), dim3(BT), args,
                               DYN_LDS, stream);
}